// Round 7
// baseline (297.016 us; speedup 1.0000x reference)
//
#include <hip/hip_runtime.h>
#include <hip/hip_bf16.h>

typedef __hip_bfloat16 bf16;
typedef __attribute__((ext_vector_type(8))) __bf16 bf16x8;
typedef __attribute__((ext_vector_type(8))) short s16x8;
typedef __attribute__((ext_vector_type(4))) float f32x4;

#define AS1 __attribute__((address_space(1)))
#define AS3 __attribute__((address_space(3)))
#define SGB __builtin_amdgcn_sched_group_barrier

#define DDIM 2048
#define KDIM 2176   // 2048 (x @ W^T) + 128 (hw @ B_cat) fused K-extension
#define CCOLS 128
#define TTOK 16384
#define NT 68       // K tiles of 32

// ---------------- K0: fp32->bf16 convert of x + fp32 router (logits, softmax, top-2) ----------------

__global__ __launch_bounds__(256) void conv_router_kernel(
    const float* __restrict__ x, const float* __restrict__ Wr, const float* __restrict__ br,
    bf16* __restrict__ xh, float* __restrict__ gates) {
  int t = blockIdx.x;
  int tid = threadIdx.x;
  f32x4 v0 = *(const f32x4*)(x + (long)t * DDIM + tid * 8);
  f32x4 v1 = *(const f32x4*)(x + (long)t * DDIM + tid * 8 + 4);
  float xv[8];
#pragma unroll
  for (int j = 0; j < 4; ++j) { xv[j] = v0[j]; xv[4 + j] = v1[j]; }
  __align__(16) bf16 tmp[8];
#pragma unroll
  for (int j = 0; j < 8; ++j) tmp[j] = __float2bfloat16(xv[j]);
  *(s16x8*)(xh + (long)t * KDIM + tid * 8) = *(const s16x8*)tmp;

  float p[6] = {0.f, 0.f, 0.f, 0.f, 0.f, 0.f};
  int d0 = tid * 8;
#pragma unroll
  for (int j = 0; j < 8; ++j) {
    const float* wrow = Wr + (d0 + j) * 6;
#pragma unroll
    for (int e = 0; e < 6; ++e) p[e] += xv[j] * wrow[e];
  }
#pragma unroll
  for (int off = 32; off > 0; off >>= 1)
#pragma unroll
    for (int e = 0; e < 6; ++e) p[e] += __shfl_down(p[e], off);
  __shared__ float red[4][6];
  int wave = tid >> 6, lane = tid & 63;
  if (lane == 0)
#pragma unroll
    for (int e = 0; e < 6; ++e) red[wave][e] = p[e];
  __syncthreads();
  if (tid == 0) {
    float g[6], mx = -1e30f;
#pragma unroll
    for (int e = 0; e < 6; ++e) {
      g[e] = red[0][e] + red[1][e] + red[2][e] + red[3][e] + br[e];
      mx = fmaxf(mx, g[e]);
    }
    float s = 0.f;
#pragma unroll
    for (int e = 0; e < 6; ++e) { g[e] = __expf(g[e] - mx); s += g[e]; }
    float inv = 1.f / s;
#pragma unroll
    for (int e = 0; e < 6; ++e) g[e] *= inv;
    int i1 = 0; float w1 = g[0];
#pragma unroll
    for (int e = 1; e < 6; ++e) if (g[e] > w1) { w1 = g[e]; i1 = e; }
    int i2 = -1; float w2 = -1.f;
#pragma unroll
    for (int e = 0; e < 6; ++e) if (e != i1 && g[e] > w2) { w2 = g[e]; i2 = e; }
#pragma unroll
    for (int e = 0; e < 6; ++e)
      gates[(long)t * 6 + e] = (e == i1) ? w1 : (e == i2) ? w2 : 0.f;
  }
}

// ---------------- prep: W_base^T -> Wcat[:, :2048], B_cat^T -> Wcat[:, 2048:], A_cat^T ----------------

__global__ __launch_bounds__(256) void convert_WT_kernel(const float* __restrict__ W,
                                                         bf16* __restrict__ Wcat) {
  __shared__ bf16 tl[64][65];
  int bi = blockIdx.x >> 5, bj = blockIdx.x & 31;
  int k0 = bi * 64, n0 = bj * 64;
  int tid = threadIdx.x;
  int r = tid >> 2, c0 = (tid & 3) << 4;
#pragma unroll
  for (int q = 0; q < 4; ++q) {
    f32x4 v = *(const f32x4*)(W + (long)(k0 + r) * DDIM + n0 + c0 + q * 4);
#pragma unroll
    for (int j = 0; j < 4; ++j) tl[r][c0 + q * 4 + j] = __float2bfloat16(v[j]);
  }
  __syncthreads();
  __align__(16) bf16 o[16];
#pragma unroll
  for (int i = 0; i < 16; ++i) o[i] = tl[c0 + i][r];
  *(s16x8*)(Wcat + (long)(n0 + r) * KDIM + k0 + c0) = *(const s16x8*)o;
  *(s16x8*)(Wcat + (long)(n0 + r) * KDIM + k0 + c0 + 8) = *(const s16x8*)(o + 8);
}

__global__ void build_AcatT(const float* __restrict__ A_s, const float* __restrict__ A_r,
                            bf16* __restrict__ AcT) {
  int idx = blockIdx.x * 256 + threadIdx.x;           // over 128*2048
  int c = idx >> 11, d = idx & 2047;
  float v = 0.f;
  if (c < 16)       v = A_s[d * 16 + c];
  else if (c < 112) { int cr = c - 16; v = A_r[((long)(cr >> 4) * DDIM + d) * 16 + (cr & 15)]; }
  AcT[(long)c * DDIM + d] = __float2bfloat16(v);
}

__global__ void build_BcatT(const float* __restrict__ B_s, const float* __restrict__ B_r,
                            bf16* __restrict__ Wcat) {
  int idx = blockIdx.x * 256 + threadIdx.x;           // over 2048*128
  int n = idx >> 7, c = idx & 127;
  float v = 0.f;
  if (c < 16)       v = B_s[c * DDIM + n];
  else if (c < 112) v = B_r[(long)(c - 16) * DDIM + n];
  Wcat[(long)n * KDIM + 2048 + c] = __float2bfloat16(v);
}

// ---------------- staging: [ROWS x 64] bf16 tile, LDS-linear (lora kernel) ----------------

template <int ROWS>
__device__ __forceinline__ void stage_tile(const bf16* __restrict__ g, long rs,
                                           bf16* lds, int wave, int lane) {
#pragma unroll
  for (int i = 0; i < (ROWS >> 5); ++i) {
    int chunk_base = (i * 4 + wave) * 64;
    int byte = (chunk_base + lane) * 16;
    int row = byte >> 7;
    int col = (byte & 127) >> 1;
    __builtin_amdgcn_global_load_lds(
        (const AS1 void*)(g + (long)row * rs + col),
        (AS3 void*)(lds + chunk_base * 8), 16, 0, 0);
  }
}

// ---------------- kernel A: H = xb @ A_cat, apply fp32 gates, write into xh[:, 2048:] ----------------

__global__ __launch_bounds__(256) void lora_kernel(
    bf16* __restrict__ xh, const bf16* __restrict__ AcT,
    const float* __restrict__ gates) {
  __shared__ __align__(16) short smem[(64 + 128) * 64];
  __shared__ float G[64][6];
  bf16* X_s = (bf16*)smem;
  bf16* B_s = (bf16*)(smem + 64 * 64);
  int tid = threadIdx.x, wave = tid >> 6, lane = tid & 63;
  long m0 = (long)blockIdx.x * 64;
  for (int i = tid; i < 384; i += 256) G[i / 6][i % 6] = gates[(m0 + i / 6) * 6 + i % 6];

  f32x4 acc[7];
#pragma unroll
  for (int i = 0; i < 7; ++i) acc[i] = f32x4{0.f, 0.f, 0.f, 0.f};

  for (int kt = 0; kt < 32; ++kt) {
    int k0 = kt * 64;
    stage_tile<64>(xh + m0 * KDIM + k0, KDIM, X_s, wave, lane);
    stage_tile<128>(AcT + k0, DDIM, B_s, wave, lane);
    __syncthreads();
#pragma unroll
    for (int kk = 0; kk < 2; ++kk) {
      bf16x8 a = *(const bf16x8*)(X_s + (16 * wave + (lane & 15)) * 64 + kk * 32 + (lane >> 4) * 8);
#pragma unroll
      for (int nr = 0; nr < 7; ++nr) {
        bf16x8 b = *(const bf16x8*)(B_s + (16 * nr + (lane & 15)) * 64 + kk * 32 + (lane >> 4) * 8);
        acc[nr] = __builtin_amdgcn_mfma_f32_16x16x32_bf16(a, b, acc[nr], 0, 0, 0);
      }
    }
    __syncthreads();
  }

#pragma unroll
  for (int nr = 0; nr < 7; ++nr) {
    int c = nr * 16 + (lane & 15);
#pragma unroll
    for (int reg = 0; reg < 4; ++reg) {
      int tl = 16 * wave + 4 * (lane >> 4) + reg;
      float wgt = (c < 16) ? 1.f : G[tl][(c - 16) >> 4];
      xh[(m0 + tl) * KDIM + 2048 + c] = __float2bfloat16(acc[nr][reg] * wgt);
    }
  }
  {
    int c = 112 + (lane & 15);
#pragma unroll
    for (int reg = 0; reg < 4; ++reg) {
      int tl = 16 * wave + 4 * (lane >> 4) + reg;
      xh[(m0 + tl) * KDIM + 2048 + c] = __float2bfloat16(0.f);
    }
  }
}

// ---------------- kernel B v5: 256x128 block, 4 waves, 16x16x32 MFMA, 3-buffer lead-3 pipeline ----
// 2 blocks/CU (72KB LDS). Invariants (audited):
//  - end-of-phase-t waitcnt: vmcnt(6) -> tiles <= t+2 resident; lgkmcnt(0) -> all frag reads of
//    this phase drained (so phase t+1 may overwrite buffer (t+1)%3).
//  - phase t: stage(t+3) overwrites buffer t%3 (reads drained last phase); readF(t+1) resident;
//    domfma consumes registers only.

__global__ __launch_bounds__(256, 2) void gemm256_kernel(
    const bf16* __restrict__ xh, const bf16* __restrict__ Wcat,
    const float* __restrict__ b_base, float* __restrict__ out) {
  extern __shared__ char sm[];
  int tid = threadIdx.x, wave = tid >> 6, lane = tid & 63;
  int wr = wave >> 1, wc = wave & 1;   // 2x2 wave grid; per-wave 128 x 64 output

  // XCD-bijective swizzle (nwg = 1024, divisible by 8)
  int bid = blockIdx.x;
  int cpx = gridDim.x >> 3;
  int swz = (bid & 7) * cpx + (bid >> 3);
  long m0 = (long)(swz >> 4) * 256;    // 64 x 16 grid
  int n0 = (swz & 15) * 128;

  // 16x16x32 frag constants (round-3 verified, conflict-free): row = lane&15, slot = lane>>4
  int cp = ((lane >> 4) << 4) ^ (((lane >> 1) & 3) << 4);
  int arow = (wr * 128 + (lane & 15)) * 64;   // A tile: 256 rows x 64B
  int brow = (wc * 64 + (lane & 15)) * 64;    // B tile: 128 rows x 64B

  float bias[4];
#pragma unroll
  for (int nf = 0; nf < 4; ++nf) bias[nf] = b_base[n0 + wc * 64 + nf * 16 + (lane & 15)];

  f32x4 acc[8][4];
#pragma unroll
  for (int i = 0; i < 8; ++i)
#pragma unroll
    for (int j = 0; j < 4; ++j) acc[i][j] = f32x4{0.f, 0.f, 0.f, 0.f};

  const bf16* Agl = xh + m0 * KDIM;
  const bf16* Bgl = Wcat + (long)n0 * KDIM;

  // stage K-tile t into buffer t%3: A 256x32 (16KB) + B 128x32 (8KB); 6 loads/thread
  auto stage = [&](int t) {
    char* dst = sm + (t % 3) * 24576;
    const bf16* gA = Agl + (long)t * 32;
#pragma unroll
    for (int k = 0; k < 4; ++k) {
      int c = k * 256 + (wave << 6) + lane;
      int row = c >> 2;
      int scol = ((((c & 3) << 4) ^ (((row >> 1) & 3) << 4)) >> 1);
      __builtin_amdgcn_global_load_lds((const AS1 void*)(gA + (long)row * KDIM + scol),
                                       (AS3 void*)(dst + c * 16), 16, 0, 0);
    }
    const bf16* gB = Bgl + (long)t * 32;
    char* db = dst + 16384;
#pragma unroll
    for (int k = 0; k < 2; ++k) {
      int c = k * 256 + (wave << 6) + lane;
      int row = c >> 2;
      int scol = ((((c & 3) << 4) ^ (((row >> 1) & 3) << 4)) >> 1);
      __builtin_amdgcn_global_load_lds((const AS1 void*)(gB + (long)row * KDIM + scol),
                                       (AS3 void*)(db + c * 16), 16, 0, 0);
    }
  };

  auto readF = [&](int t, bf16x8 (&a)[8], bf16x8 (&b)[4]) {
    char* Ab = sm + (t % 3) * 24576;
    char* Bb = Ab + 16384;
#pragma unroll
    for (int mf = 0; mf < 8; ++mf)
      a[mf] = *(const bf16x8*)(Ab + arow + mf * 1024 + cp);
#pragma unroll
    for (int nf = 0; nf < 4; ++nf)
      b[nf] = *(const bf16x8*)(Bb + brow + nf * 1024 + cp);
  };

  auto domfma = [&](bf16x8 (&a)[8], bf16x8 (&b)[4]) {
#pragma unroll
    for (int mf = 0; mf < 8; ++mf)
#pragma unroll
      for (int nf = 0; nf < 4; ++nf)
        acc[mf][nf] = __builtin_amdgcn_mfma_f32_16x16x32_bf16(a[mf], b[nf], acc[mf][nf], 0, 0, 0);
  };

  // pin per-phase interleave: 6 global_load_lds first, then (3 ds_read, 8 mfma) x 4
  auto pin = [&]() {
    SGB(0x020, 6, 0);                 // VMEM_READ: stage(t+3)
#pragma unroll
    for (int g = 0; g < 4; ++g) {
      SGB(0x100, 3, 0);               // DS_READ: readF(t+1)
      SGB(0x008, 8, 0);               // MFMA: domfma(t)
    }
  };

  bf16x8 a0[8], b0[4], a1[8], b1[4];

  // prologue: stage 0..2; vmcnt(6) -> tiles 0,1 resident (tile 2 in flight); read frags(0);
  // drain frag reads + barrier so phase 0 may overwrite buffer 0.
  stage(0); stage(1); stage(2);
  asm volatile("s_waitcnt vmcnt(6)" ::: "memory");
  __builtin_amdgcn_s_barrier();
  readF(0, a0, b0);
  asm volatile("s_waitcnt lgkmcnt(0)" ::: "memory");
  __builtin_amdgcn_sched_barrier(0);
  __builtin_amdgcn_s_barrier();

  // main loop: phases 0..63 paired; phase t: stage(t+3), readF(t+1), domfma(t)
  for (int it = 0; it < 32; ++it) {
    int t = it * 2;
    stage(t + 3);
    readF(t + 1, a1, b1);
    domfma(a0, b0);
    pin();
    asm volatile("s_waitcnt vmcnt(6) lgkmcnt(0)" ::: "memory");
    __builtin_amdgcn_sched_barrier(0);
    __builtin_amdgcn_s_barrier();

    stage(t + 4);
    readF(t + 2, a0, b0);
    domfma(a1, b1);
    pin();
    asm volatile("s_waitcnt vmcnt(6) lgkmcnt(0)" ::: "memory");
    __builtin_amdgcn_sched_barrier(0);
    __builtin_amdgcn_s_barrier();
  }
  // tail: phases 64..67 (a0 = frags(64); stages 3..66 issued; stage(66) in flight)
  stage(67);
  readF(65, a1, b1);
  domfma(a0, b0);
  pin();
  asm volatile("s_waitcnt vmcnt(6) lgkmcnt(0)" ::: "memory");
  __builtin_amdgcn_sched_barrier(0);
  __builtin_amdgcn_s_barrier();

  readF(66, a0, b0);
  domfma(a1, b1);
  asm volatile("s_waitcnt vmcnt(0) lgkmcnt(0)" ::: "memory");
  __builtin_amdgcn_sched_barrier(0);
  __builtin_amdgcn_s_barrier();

  readF(67, a1, b1);
  domfma(a0, b0);
  domfma(a1, b1);

  // epilogue: direct fp32 stores (64B contiguous per 16-lane group), bias add
#pragma unroll
  for (int mf = 0; mf < 8; ++mf)
#pragma unroll
    for (int nf = 0; nf < 4; ++nf) {
      long gc = n0 + wc * 64 + nf * 16 + (lane & 15);
#pragma unroll
      for (int reg = 0; reg < 4; ++reg) {
        long gr = m0 + wr * 128 + mf * 16 + 4 * (lane >> 4) + reg;
        out[gr * DDIM + gc] = acc[mf][nf][reg] + bias[nf];
      }
    }
}

// ---------------- launcher ----------------

extern "C" void kernel_launch(void* const* d_in, const int* in_sizes, int n_in,
                              void* d_out, int out_size, void* d_ws, size_t ws_size,
                              hipStream_t stream) {
  const float* x        = (const float*)d_in[0];
  const float* W_base   = (const float*)d_in[1];
  const float* b_base   = (const float*)d_in[2];
  const float* A_s      = (const float*)d_in[3];
  const float* B_s      = (const float*)d_in[4];
  const float* A_r      = (const float*)d_in[5];
  const float* B_r      = (const float*)d_in[6];
  const float* W_router = (const float*)d_in[7];
  const float* b_router = (const float*)d_in[8];
  float* out = (float*)d_out;

  char* ws = (char*)d_ws;
  bf16*  xh    = (bf16*)(ws);                    // 16384*2176*2 = 71,303,168 B
  bf16*  Wcat  = (bf16*)(ws + 71303168);         //  2048*2176*2 =  8,912,896 B
  bf16*  AcT   = (bf16*)(ws + 80216064);         //   128*2048*2 =    524,288 B
  float* gates = (float*)(ws + 80740352);        //   16384*6*4  =    393,216 B

  (void)hipFuncSetAttribute((const void*)gemm256_kernel,
                            hipFuncAttributeMaxDynamicSharedMemorySize, 73728);

  conv_router_kernel<<<TTOK, 256, 0, stream>>>(x, W_router, b_router, xh, gates);
  convert_WT_kernel<<<1024, 256, 0, stream>>>(W_base, Wcat);
  build_AcatT<<<1024, 256, 0, stream>>>(A_s, A_r, AcT);
  build_BcatT<<<1024, 256, 0, stream>>>(B_s, B_r, Wcat);
  lora_kernel<<<256, 256, 0, stream>>>(xh, AcT, gates);
  gemm256_kernel<<<1024, 256, 73728, stream>>>(xh, Wcat, b_base, out);
}

// Round 8
// 276.576 us; speedup vs baseline: 1.0739x; 1.0739x over previous
//
#include <hip/hip_runtime.h>
#include <hip/hip_bf16.h>

typedef __hip_bfloat16 bf16;
typedef __attribute__((ext_vector_type(8))) __bf16 bf16x8;
typedef __attribute__((ext_vector_type(8))) short s16x8;
typedef __attribute__((ext_vector_type(4))) float f32x4;

#define AS1 __attribute__((address_space(1)))
#define AS3 __attribute__((address_space(3)))

#define DDIM 2048
#define KDIM 2176   // 2048 (x @ W^T) + 128 (hw @ B_cat) fused K-extension
#define TTOK 16384
// K-tiles of 64: 34 total; main loop 16 iters x 2 tiles; tail = tiles 32,33

// ---------------- K0: fp32->bf16 convert of x + fp32 router (logits, softmax, top-2) ----------------

__global__ __launch_bounds__(256) void conv_router_kernel(
    const float* __restrict__ x, const float* __restrict__ Wr, const float* __restrict__ br,
    bf16* __restrict__ xh, float* __restrict__ gates) {
  int t = blockIdx.x;
  int tid = threadIdx.x;
  f32x4 v0 = *(const f32x4*)(x + (long)t * DDIM + tid * 8);
  f32x4 v1 = *(const f32x4*)(x + (long)t * DDIM + tid * 8 + 4);
  float xv[8];
#pragma unroll
  for (int j = 0; j < 4; ++j) { xv[j] = v0[j]; xv[4 + j] = v1[j]; }
  __align__(16) bf16 tmp[8];
#pragma unroll
  for (int j = 0; j < 8; ++j) tmp[j] = __float2bfloat16(xv[j]);
  *(s16x8*)(xh + (long)t * KDIM + tid * 8) = *(const s16x8*)tmp;

  float p[6] = {0.f, 0.f, 0.f, 0.f, 0.f, 0.f};
  int d0 = tid * 8;
#pragma unroll
  for (int j = 0; j < 8; ++j) {
    const float* wrow = Wr + (d0 + j) * 6;
#pragma unroll
    for (int e = 0; e < 6; ++e) p[e] += xv[j] * wrow[e];
  }
#pragma unroll
  for (int off = 32; off > 0; off >>= 1)
#pragma unroll
    for (int e = 0; e < 6; ++e) p[e] += __shfl_down(p[e], off);
  __shared__ float red[4][6];
  int wave = tid >> 6, lane = tid & 63;
  if (lane == 0)
#pragma unroll
    for (int e = 0; e < 6; ++e) red[wave][e] = p[e];
  __syncthreads();
  if (tid == 0) {
    float g[6], mx = -1e30f;
#pragma unroll
    for (int e = 0; e < 6; ++e) {
      g[e] = red[0][e] + red[1][e] + red[2][e] + red[3][e] + br[e];
      mx = fmaxf(mx, g[e]);
    }
    float s = 0.f;
#pragma unroll
    for (int e = 0; e < 6; ++e) { g[e] = __expf(g[e] - mx); s += g[e]; }
    float inv = 1.f / s;
#pragma unroll
    for (int e = 0; e < 6; ++e) g[e] *= inv;
    int i1 = 0; float w1 = g[0];
#pragma unroll
    for (int e = 1; e < 6; ++e) if (g[e] > w1) { w1 = g[e]; i1 = e; }
    int i2 = -1; float w2 = -1.f;
#pragma unroll
    for (int e = 0; e < 6; ++e) if (e != i1 && g[e] > w2) { w2 = g[e]; i2 = e; }
#pragma unroll
    for (int e = 0; e < 6; ++e)
      gates[(long)t * 6 + e] = (e == i1) ? w1 : (e == i2) ? w2 : 0.f;
  }
}

// ---------------- prep: W_base^T -> Wcat[:, :2048], B_cat^T -> Wcat[:, 2048:], A_cat^T ----------------

__global__ __launch_bounds__(256) void convert_WT_kernel(const float* __restrict__ W,
                                                         bf16* __restrict__ Wcat) {
  __shared__ bf16 tl[64][65];
  int bi = blockIdx.x >> 5, bj = blockIdx.x & 31;
  int k0 = bi * 64, n0 = bj * 64;
  int tid = threadIdx.x;
  int r = tid >> 2, c0 = (tid & 3) << 4;
#pragma unroll
  for (int q = 0; q < 4; ++q) {
    f32x4 v = *(const f32x4*)(W + (long)(k0 + r) * DDIM + n0 + c0 + q * 4);
#pragma unroll
    for (int j = 0; j < 4; ++j) tl[r][c0 + q * 4 + j] = __float2bfloat16(v[j]);
  }
  __syncthreads();
  __align__(16) bf16 o[16];
#pragma unroll
  for (int i = 0; i < 16; ++i) o[i] = tl[c0 + i][r];
  *(s16x8*)(Wcat + (long)(n0 + r) * KDIM + k0 + c0) = *(const s16x8*)o;
  *(s16x8*)(Wcat + (long)(n0 + r) * KDIM + k0 + c0 + 8) = *(const s16x8*)(o + 8);
}

__global__ void build_AcatT(const float* __restrict__ A_s, const float* __restrict__ A_r,
                            bf16* __restrict__ AcT) {
  int idx = blockIdx.x * 256 + threadIdx.x;           // over 128*2048
  int c = idx >> 11, d = idx & 2047;
  float v = 0.f;
  if (c < 16)       v = A_s[d * 16 + c];
  else if (c < 112) { int cr = c - 16; v = A_r[((long)(cr >> 4) * DDIM + d) * 16 + (cr & 15)]; }
  AcT[(long)c * DDIM + d] = __float2bfloat16(v);
}

__global__ void build_BcatT(const float* __restrict__ B_s, const float* __restrict__ B_r,
                            bf16* __restrict__ Wcat) {
  int idx = blockIdx.x * 256 + threadIdx.x;           // over 2048*128
  int n = idx >> 7, c = idx & 127;
  float v = 0.f;
  if (c < 16)       v = B_s[c * DDIM + n];
  else if (c < 112) v = B_r[(long)(c - 16) * DDIM + n];
  Wcat[(long)n * KDIM + 2048 + c] = __float2bfloat16(v);
}

// ---------------- staging: [ROWS x 64] bf16 tile, LDS-linear (lora kernel) ----------------

template <int ROWS>
__device__ __forceinline__ void stage_tile(const bf16* __restrict__ g, long rs,
                                           bf16* lds, int wave, int lane) {
#pragma unroll
  for (int i = 0; i < (ROWS >> 5); ++i) {
    int chunk_base = (i * 4 + wave) * 64;
    int byte = (chunk_base + lane) * 16;
    int row = byte >> 7;
    int col = (byte & 127) >> 1;
    __builtin_amdgcn_global_load_lds(
        (const AS1 void*)(g + (long)row * rs + col),
        (AS3 void*)(lds + chunk_base * 8), 16, 0, 0);
  }
}

// ---------------- kernel A: H = xb @ A_cat, apply fp32 gates, write into xh[:, 2048:] ----------------

__global__ __launch_bounds__(256) void lora_kernel(
    bf16* __restrict__ xh, const bf16* __restrict__ AcT,
    const float* __restrict__ gates) {
  __shared__ __align__(16) short smem[(64 + 128) * 64];
  __shared__ float G[64][6];
  bf16* X_s = (bf16*)smem;
  bf16* B_s = (bf16*)(smem + 64 * 64);
  int tid = threadIdx.x, wave = tid >> 6, lane = tid & 63;
  long m0 = (long)blockIdx.x * 64;
  for (int i = tid; i < 384; i += 256) G[i / 6][i % 6] = gates[(m0 + i / 6) * 6 + i % 6];

  f32x4 acc[7];
#pragma unroll
  for (int i = 0; i < 7; ++i) acc[i] = f32x4{0.f, 0.f, 0.f, 0.f};

  for (int kt = 0; kt < 32; ++kt) {
    int k0 = kt * 64;
    stage_tile<64>(xh + m0 * KDIM + k0, KDIM, X_s, wave, lane);
    stage_tile<128>(AcT + k0, DDIM, B_s, wave, lane);
    __syncthreads();
#pragma unroll
    for (int kk = 0; kk < 2; ++kk) {
      bf16x8 a = *(const bf16x8*)(X_s + (16 * wave + (lane & 15)) * 64 + kk * 32 + (lane >> 4) * 8);
#pragma unroll
      for (int nr = 0; nr < 7; ++nr) {
        bf16x8 b = *(const bf16x8*)(B_s + (16 * nr + (lane & 15)) * 64 + kk * 32 + (lane >> 4) * 8);
        acc[nr] = __builtin_amdgcn_mfma_f32_16x16x32_bf16(a, b, acc[nr], 0, 0, 0);
      }
    }
    __syncthreads();
  }

#pragma unroll
  for (int nr = 0; nr < 7; ++nr) {
    int c = nr * 16 + (lane & 15);
#pragma unroll
    for (int reg = 0; reg < 4; ++reg) {
      int tl = 16 * wave + 4 * (lane >> 4) + reg;
      float wgt = (c < 16) ? 1.f : G[tl][(c - 16) >> 4];
      xh[(m0 + tl) * KDIM + 2048 + c] = __float2bfloat16(acc[nr][reg] * wgt);
    }
  }
  {
    int c = 112 + (lane & 15);
#pragma unroll
    for (int reg = 0; reg < 4; ++reg) {
      int tl = 16 * wave + 4 * (lane >> 4) + reg;
      xh[(m0 + tl) * KDIM + 2048 + c] = __float2bfloat16(0.f);
    }
  }
}

// ---------------- kernel B v6: m201-style 256x256 8-phase template, BK=64 ----------------
// 8 waves (2x4), per-wave 128x64 out. LDS: 2 K-tile buffers x (A 4 subtiles + B 4 subtiles)
// of 128rows x 32cols (8KB each) = 128KB. Phase = {ds_reads + 2 gload_lds -> barrier ->
// lgkmcnt(0) -> setprio+16 MFMA -> counted vmcnt -> barrier}. Subtile staged 4 phases
// before first read; overwrite target drained 2 phases prior (audited).

__global__ __launch_bounds__(512, 2) void gemm256_kernel(
    const bf16* __restrict__ xh, const bf16* __restrict__ Wcat,
    const float* __restrict__ b_base, float* __restrict__ out) {
  extern __shared__ char sm[];
  int tid = threadIdx.x, wave = tid >> 6, lane = tid & 63;
  int wr = wave >> 2, wc = wave & 3;   // 2x4 wave grid; per-wave 128 x 64 output

  // XCD-bijective swizzle (nwg = 512, divisible by 8); consecutive swz share A panel
  int bid = blockIdx.x;
  int cpx = gridDim.x >> 3;
  int swz = (bid & 7) * cpx + (bid >> 3);
  long m0 = (long)(swz >> 3) * 256;    // 64 x 8 grid
  int n0 = (swz & 7) * 256;

  // proven-0-conflict frag constants: row = lane&15, slot = lane>>4, XOR ((lane>>1)&3)<<4
  int cp = ((lane >> 4) << 4) ^ (((lane >> 1) & 3) << 4);

  float bias[4];
#pragma unroll
  for (int nf = 0; nf < 4; ++nf) bias[nf] = b_base[n0 + wc * 64 + nf * 16 + (lane & 15)];

  f32x4 acc[8][4];
#pragma unroll
  for (int i = 0; i < 8; ++i)
#pragma unroll
    for (int j = 0; j < 4; ++j) acc[i][j] = f32x4{0.f, 0.f, 0.f, 0.f};

  const bf16* Agl = xh + m0 * KDIM;
  const bf16* Bgl = Wcat + (long)n0 * KDIM;

  // stage one 8KB subtile (op: 0=A,1=B; half h; ks s) of K-tile t: 1 load/thread
  auto stage_sub = [&](int t, int op, int h, int s) {
    int row = tid >> 2;
    int scol = ((((tid & 3) << 4) ^ (((row >> 1) & 3) << 4)) >> 1);
    const bf16* src = (op ? Bgl : Agl) + (long)(h * 128 + row) * KDIM + t * 64 + s * 32 + scol;
    char* dst = sm + (t & 1) * 65536 + op * 32768 + (h * 2 + s) * 8192 + tid * 16;
    __builtin_amdgcn_global_load_lds((const AS1 void*)src, (AS3 void*)dst, 16, 0, 0);
  };

  bf16x8 a[4], b[4];

  // phase: quadrant (ks, mh) of K-tile in buffer `buf`; optional stage of 2 subtiles; counted vmcnt
  auto phase = [&](int buf, int ks, int mh, bool doStage, int stT, int stOp, int stKs, int vm) {
    if (mh == 0) {
      char* Bb = sm + buf * 65536 + 32768 + ((wc >> 1) * 2 + ks) * 8192;
#pragma unroll
      for (int n = 0; n < 4; ++n)
        b[n] = *(const bf16x8*)(Bb + ((wc & 1) * 64 + n * 16 + (lane & 15)) * 64 + cp);
    }
    char* Ab = sm + buf * 65536 + (wr * 2 + ks) * 8192;
#pragma unroll
    for (int j = 0; j < 4; ++j)
      a[j] = *(const bf16x8*)(Ab + ((mh * 4 + j) * 16 + (lane & 15)) * 64 + cp);
    if (doStage) { stage_sub(stT, stOp, 0, stKs); stage_sub(stT, stOp, 1, stKs); }
    __builtin_amdgcn_sched_barrier(0);
    __builtin_amdgcn_s_barrier();
    asm volatile("s_waitcnt lgkmcnt(0)" ::: "memory");
    __builtin_amdgcn_sched_barrier(0);
    __builtin_amdgcn_s_setprio(1);
#pragma unroll
    for (int j = 0; j < 4; ++j)
#pragma unroll
      for (int n = 0; n < 4; ++n)
        acc[mh * 4 + j][n] = __builtin_amdgcn_mfma_f32_16x16x32_bf16(a[j], b[n], acc[mh * 4 + j][n], 0, 0, 0);
    __builtin_amdgcn_s_setprio(0);
    __builtin_amdgcn_sched_barrier(0);
    if (vm == 6)      asm volatile("s_waitcnt vmcnt(6)" ::: "memory");
    else if (vm == 4) asm volatile("s_waitcnt vmcnt(4)" ::: "memory");
    else if (vm == 0) asm volatile("s_waitcnt vmcnt(0)" ::: "memory");
    __builtin_amdgcn_s_barrier();
  };

  // prologue: stage t0 ks0+ks1, t1 ks0 (12 loads/thread); t0ks0 resident after vmcnt(8)+barrier
  stage_sub(0, 0, 0, 0); stage_sub(0, 0, 1, 0); stage_sub(0, 1, 0, 0); stage_sub(0, 1, 1, 0);
  stage_sub(0, 0, 0, 1); stage_sub(0, 0, 1, 1); stage_sub(0, 1, 0, 1); stage_sub(0, 1, 1, 1);
  stage_sub(1, 0, 0, 0); stage_sub(1, 0, 1, 0); stage_sub(1, 1, 0, 0); stage_sub(1, 1, 1, 0);
  asm volatile("s_waitcnt vmcnt(8)" ::: "memory");
  __builtin_amdgcn_s_barrier();

  // main loop: K-tiles 0..31; per K-tile t: q0 stages (t+1)A-ks1, q1 (t+1)B-ks1,
  // q2 (t+2)A-ks0, q3 (t+2)B-ks0 (dest buffers correct by t parity)
  for (int i = 0; i < 16; ++i) {
    int t0 = 2 * i;
    phase(0, 0, 0, true, t0 + 1, 0, 1, 6);
    phase(0, 0, 1, true, t0 + 1, 1, 1, 6);
    phase(0, 1, 0, true, t0 + 2, 0, 0, 6);
    phase(0, 1, 1, true, t0 + 2, 1, 0, 6);
    phase(1, 0, 0, true, t0 + 2, 0, 1, 6);
    phase(1, 0, 1, true, t0 + 2, 1, 1, 6);
    phase(1, 1, 0, true, t0 + 3, 0, 0, 6);
    phase(1, 1, 1, true, t0 + 3, 1, 0, 6);
  }
  // tail: t=32 (buf0) stages only 33-ks1; t=33 (buf1) stages nothing.
  // waits audited: 6,6,4,4 then 0 at t33-q0 (33ks1 needed at t33-q2).
  phase(0, 0, 0, true, 33, 0, 1, 6);
  phase(0, 0, 1, true, 33, 1, 1, 6);
  phase(0, 1, 0, false, 0, 0, 0, 4);
  phase(0, 1, 1, false, 0, 0, 0, 4);
  phase(1, 0, 0, false, 0, 0, 0, 0);
  phase(1, 0, 1, false, 0, 0, 0, -1);
  phase(1, 1, 0, false, 0, 0, 0, -1);
  phase(1, 1, 1, false, 0, 0, 0, -1);

  // epilogue: bias add, fp32 LDS repack in 2 passes (128 rows x 256 cols = 128KB),
  // XOR key (r>>2)&3 << 6 (2-way max on writes), 1024B-coalesced float4 stores
  float* Cs = (float*)sm;
#pragma unroll
  for (int p = 0; p < 2; ++p) {
    __syncthreads();
#pragma unroll
    for (int q = 0; q < 4; ++q) {
#pragma unroll
      for (int nf = 0; nf < 4; ++nf) {
#pragma unroll
        for (int reg = 0; reg < 4; ++reg) {
          int r = wr * 64 + q * 16 + 4 * (lane >> 4) + reg;
          int colb = ((wc * 64 + nf * 16 + (lane & 15)) * 4) ^ (((r >> 2) & 3) << 6);
          *(float*)((char*)Cs + r * 1024 + colb) = acc[p * 4 + q][nf][reg] + bias[nf];
        }
      }
    }
    __syncthreads();
#pragma unroll 4
    for (int it = 0; it < 16; ++it) {
      int v = it * 512 + tid;
      int r = v >> 6, slot = v & 63;
      f32x4 val = *(const f32x4*)((char*)Cs + r * 1024 + ((slot << 4) ^ (((r >> 2) & 3) << 6)));
      long grow = m0 + (r >> 6) * 128 + p * 64 + (r & 63);
      *(f32x4*)(out + grow * DDIM + n0 + slot * 4) = val;
    }
  }
}

// ---------------- launcher ----------------

extern "C" void kernel_launch(void* const* d_in, const int* in_sizes, int n_in,
                              void* d_out, int out_size, void* d_ws, size_t ws_size,
                              hipStream_t stream) {
  const float* x        = (const float*)d_in[0];
  const float* W_base   = (const float*)d_in[1];
  const float* b_base   = (const float*)d_in[2];
  const float* A_s      = (const float*)d_in[3];
  const float* B_s      = (const float*)d_in[4];
  const float* A_r      = (const float*)d_in[5];
  const float* B_r      = (const float*)d_in[6];
  const float* W_router = (const float*)d_in[7];
  const float* b_router = (const float*)d_in[8];
  float* out = (float*)d_out;

  char* ws = (char*)d_ws;
  bf16*  xh    = (bf16*)(ws);                    // 16384*2176*2 = 71,303,168 B
  bf16*  Wcat  = (bf16*)(ws + 71303168);         //  2048*2176*2 =  8,912,896 B
  bf16*  AcT   = (bf16*)(ws + 80216064);         //   128*2048*2 =    524,288 B
  float* gates = (float*)(ws + 80740352);        //   16384*6*4  =    393,216 B

  (void)hipFuncSetAttribute((const void*)gemm256_kernel,
                            hipFuncAttributeMaxDynamicSharedMemorySize, 131072);

  conv_router_kernel<<<TTOK, 256, 0, stream>>>(x, W_router, b_router, xh, gates);
  convert_WT_kernel<<<1024, 256, 0, stream>>>(W_base, Wcat);
  build_AcatT<<<1024, 256, 0, stream>>>(A_s, A_r, AcT);
  build_BcatT<<<1024, 256, 0, stream>>>(B_s, B_r, Wcat);
  lora_kernel<<<256, 256, 0, stream>>>(xh, AcT, gates);
  gemm256_kernel<<<512, 512, 131072, stream>>>(xh, Wcat, b_base, out);
}